// Round 18
// baseline (182.768 us; speedup 1.0000x reference)
//
#include <hip/hip_runtime.h>
#include <cstdint>
#include <math.h>

// ---------- types ----------
typedef __attribute__((ext_vector_type(8))) short bf16x8;   // MFMA A/B operand (4 VGPRs)
typedef __attribute__((ext_vector_type(4))) float f32x4;    // MFMA C/D operand
typedef __attribute__((ext_vector_type(4))) unsigned short u16x4;

__device__ __forceinline__ unsigned short f2bf(float f) {
  union { float f; unsigned int u; } c; c.f = f;
  unsigned int u = c.u;
  return (unsigned short)((u + 0x7FFFu + ((u >> 16) & 1u)) >> 16);  // RNE
}
__device__ __forceinline__ float bf2f(unsigned short u) {
  return __uint_as_float(((unsigned int)u) << 16);
}

// pack hi16(a) | hi16(b)<<16 via v_perm_b32 (1 VALU op; trunc-to-bf16)
__device__ __forceinline__ unsigned int pack_trunc(float a, float b) {
  return __builtin_amdgcn_perm(__float_as_uint(b), __float_as_uint(a), 0x07060302u);
}

__device__ __forceinline__ float fmax3(float a, float b, float c) {
  return fmaxf(fmaxf(a, b), c);  // clang fuses to v_max3_f32
}

__device__ __forceinline__ void gload_lds16(const void* g, void* l) {
  __builtin_amdgcn_global_load_lds(
      (const __attribute__((address_space(1))) unsigned int*)g,
      (__attribute__((address_space(3))) unsigned int*)l, 16, 0, 0);
}

// counted-vmcnt barrier (T4): wait only the oldest loads, never full drain
#define FSYNC(N) do {                                        \
    asm volatile("s_waitcnt vmcnt(" N ")" ::: "memory");     \
    __builtin_amdgcn_s_barrier();                            \
    __builtin_amdgcn_sched_barrier(0);                       \
  } while (0)

// ---------- prep: weight transposes (blocks 0..4095) + fp32->bf16 converts ----------
__global__ __launch_bounds__(256)
void k_prep(const float* __restrict__ x, unsigned short* __restrict__ xb,
            const float* __restrict__ out_w, unsigned short* __restrict__ OwB,
            const float* __restrict__ w0, const float* __restrict__ w1,
            const float* __restrict__ w2, const float* __restrict__ w3,
            unsigned short* __restrict__ o012, unsigned short* __restrict__ o3) {
  __shared__ float t[32][33];
  const int b = blockIdx.x;
  if (b < 4096) {
    const int m = b >> 10, rem = b & 1023;
    const float* in = m == 0 ? w0 : m == 1 ? w1 : m == 2 ? w2 : w3;
    unsigned short* out = m < 3 ? o012 + (size_t)m * 1048576 : o3;
    const int r0 = (rem >> 5) << 5, c0 = (rem & 31) << 5;
    const int tx = threadIdx.x & 31, ty = threadIdx.x >> 5;  // 32 x 8
#pragma unroll
    for (int rr = ty; rr < 32; rr += 8) t[rr][tx] = in[(size_t)(r0 + rr) * 1024 + c0 + tx];
    __syncthreads();
#pragma unroll
    for (int cc = ty; cc < 32; cc += 8)
      out[(size_t)(c0 + cc) * 1024 + r0 + tx] = f2bf(t[tx][cc]);
  } else {
    int i = (b - 4096) * 256 + threadIdx.x;
    const float* in;
    unsigned short* out;
    if (i < 1048576) { in = x; out = xb; }
    else { i -= 1048576; if (i >= 262144) return; in = out_w; out = OwB; }
    float4 v = ((const float4*)in)[i];
    u16x4 o;
    o.x = f2bf(v.x); o.y = f2bf(v.y); o.z = f2bf(v.z); o.w = f2bf(v.w);
    ((u16x4*)out)[i] = o;
  }
}

// ---------- bf16 GEMM 128x128, dbuf + 1 barrier/K-step (T3-min) ----------
// MODE 0: fp32 C.  MODE 1: bf16 C.  MODE 2: bf16 C for n0<VCOL0; cols >= VCOL0
// are written TRANSPOSED to VT[col-VCOL0][rowPerm] (fused V-transpose, with the
// per-64-tile kv permutation so flash PV reads are single b128 under perm pi).
template <int MODE>
__global__ __launch_bounds__(256)
void k_gemm_bt(const unsigned short* __restrict__ A, const unsigned short* __restrict__ BT,
               void* __restrict__ C, unsigned short* __restrict__ VT,
               int M, int N, int K) {
  const int VCOL0 = 2048;
  __shared__ __align__(16) unsigned short As[2][128 * 32];
  __shared__ __align__(16) unsigned short Bs[2][128 * 32];
  const int tid = threadIdx.x;
  const int wid = tid >> 6, lane = tid & 63;
  const int l16 = lane & 15, krow = lane >> 4;
  const int m0 = blockIdx.x * 128, n0 = blockIdx.y * 128;
  const int wr = wid >> 1, wc = wid & 1;  // 2x2 waves, 64x64 each

  f32x4 acc[4][4] = {};

  auto stageG = [&](int buf, int k0) {
#pragma unroll
    for (int j = 0; j < 2; j++) {
      int f = j * 256 + tid;
      gload_lds16(A  + (size_t)(m0 + (f >> 2)) * K + k0 + (f & 3) * 8,
                  (char*)As[buf] + (size_t)(j * 256 + wid * 64) * 16);
      gload_lds16(BT + (size_t)(n0 + (f >> 2)) * K + k0 + (f & 3) * 8,
                  (char*)Bs[buf] + (size_t)(j * 256 + wid * 64) * 16);
    }
  };
  auto comp = [&](int buf) {
    bf16x8 a[4], b[4];
#pragma unroll
    for (int i = 0; i < 4; i++) {
      a[i] = *(const bf16x8*)&As[buf][(wr * 64 + i * 16 + l16) * 32 + krow * 8];
      b[i] = *(const bf16x8*)&Bs[buf][(wc * 64 + i * 16 + l16) * 32 + krow * 8];
    }
#pragma unroll
    for (int mi = 0; mi < 4; mi++)
#pragma unroll
      for (int ni = 0; ni < 4; ni++)
        acc[mi][ni] = __builtin_amdgcn_mfma_f32_16x16x32_bf16(a[mi], b[ni], acc[mi][ni], 0, 0, 0);
  };

  stageG(0, 0);
  __syncthreads();
  for (int k0 = 0; k0 < K; k0 += 64) {
    if (k0 + 32 < K) stageG(1, k0 + 32);
    comp(0);
    __syncthreads();
    if (k0 + 64 < K) stageG(0, k0 + 64);
    comp(1);
    __syncthreads();
  }

  if (MODE == 2 && n0 >= VCOL0) {
    // V region: write transposed to VT[col - VCOL0][rowPerm]; rows consecutive per
    // lane (r=0..3) stay contiguous under the kv permutation (r bits unchanged).
#pragma unroll
    for (int mi = 0; mi < 4; mi++)
#pragma unroll
      for (int ni = 0; ni < 4; ni++) {
        int col = n0 - VCOL0 + wc * 64 + ni * 16 + l16;
        int row = m0 + wr * 64 + mi * 16 + krow * 4;
        int u0 = row & 63;
        int rowp = (row & ~63) | (u0 & 32) | ((u0 & 12) << 1) | (((u0 >> 4) & 1) << 2);
        uint2 w;
        w.x = (unsigned)f2bf(acc[mi][ni][0]) | ((unsigned)f2bf(acc[mi][ni][1]) << 16);
        w.y = (unsigned)f2bf(acc[mi][ni][2]) | ((unsigned)f2bf(acc[mi][ni][3]) << 16);
        *(uint2*)&VT[(size_t)col * 4096 + rowp] = w;
      }
    return;
  }

#pragma unroll
  for (int mi = 0; mi < 4; mi++)
#pragma unroll
    for (int ni = 0; ni < 4; ni++)
#pragma unroll
      for (int r = 0; r < 4; r++) {
        int row = m0 + wr * 64 + mi * 16 + krow * 4 + r;
        int col = n0 + wc * 64 + ni * 16 + l16;
        float v = acc[mi][ni][r];
        if (MODE) ((unsigned short*)C)[(size_t)row * N + col] = f2bf(v);
        else      ((float*)C)[(size_t)row * N + col] = v;
      }
}

// ---------- bf16 GEMM 128x64, dbuf + 1 barrier/K-step ----------
template <int OUTBF>
__global__ __launch_bounds__(256)
void k_gemm_bt_n64(const unsigned short* __restrict__ A, const unsigned short* __restrict__ BT,
                   void* __restrict__ C, int M, int N, int K) {
  __shared__ __align__(16) unsigned short As[2][128 * 32];
  __shared__ __align__(16) unsigned short Bs[2][64 * 32];
  const int tid = threadIdx.x;
  const int wid = tid >> 6, lane = tid & 63;
  const int l16 = lane & 15, krow = lane >> 4;
  const int m0 = blockIdx.x * 128, n0 = blockIdx.y * 64;
  const int wr = wid >> 1, wc = wid & 1;  // 2x2 waves, 64x32 each

  f32x4 acc[4][2] = {};

  auto stageG = [&](int buf, int k0) {
#pragma unroll
    for (int j = 0; j < 2; j++) {
      int f = j * 256 + tid;
      gload_lds16(A + (size_t)(m0 + (f >> 2)) * K + k0 + (f & 3) * 8,
                  (char*)As[buf] + (size_t)(j * 256 + wid * 64) * 16);
    }
    gload_lds16(BT + (size_t)(n0 + (tid >> 2)) * K + k0 + (tid & 3) * 8,
                (char*)Bs[buf] + (size_t)(wid * 64) * 16);
  };
  auto comp = [&](int buf) {
    bf16x8 a[4], b[2];
#pragma unroll
    for (int i = 0; i < 4; i++)
      a[i] = *(const bf16x8*)&As[buf][(wr * 64 + i * 16 + l16) * 32 + krow * 8];
#pragma unroll
    for (int i = 0; i < 2; i++)
      b[i] = *(const bf16x8*)&Bs[buf][(wc * 32 + i * 16 + l16) * 32 + krow * 8];
#pragma unroll
    for (int mi = 0; mi < 4; mi++)
#pragma unroll
      for (int ni = 0; ni < 2; ni++)
        acc[mi][ni] = __builtin_amdgcn_mfma_f32_16x16x32_bf16(a[mi], b[ni], acc[mi][ni], 0, 0, 0);
  };

  stageG(0, 0);
  __syncthreads();
  for (int k0 = 0; k0 < K; k0 += 64) {
    if (k0 + 32 < K) stageG(1, k0 + 32);
    comp(0);
    __syncthreads();
    if (k0 + 64 < K) stageG(0, k0 + 64);
    comp(1);
    __syncthreads();
  }

#pragma unroll
  for (int mi = 0; mi < 4; mi++)
#pragma unroll
    for (int ni = 0; ni < 2; ni++)
#pragma unroll
      for (int r = 0; r < 4; r++) {
        int row = m0 + wr * 64 + mi * 16 + krow * 4 + r;
        int col = n0 + wc * 32 + ni * 16 + l16;
        float v = acc[mi][ni][r];
        if (OUTBF) ((unsigned short*)C)[(size_t)row * N + col] = f2bf(v);
        else       ((float*)C)[(size_t)row * N + col] = v;
      }
}

// ---------- flash attention: Q=32/wave + full pipeline (halved LDS-read/work) ----------
// 4 waves/WG (256 thr), 128 q-rows/WG, 32 q-rows/wave, grid 512 (16 heads x 32 qb)
// -> 2 WG/CU (128 KB LDS) = 8 waves/CU. LDS 64 KB: 4 slots x (K 8KB | V 8KB),
// prefetch depth 3, counted vmcnt (8/8/4/0). K/V b128 fragments SHARED across the
// two mi q-tiles (2x LDS-read amortization vs Q=16 — the R17 wall). Vt kv-permuted
// by GEMM1 so PV V A-frag is a single b128 at koff+8192.
__global__ __launch_bounds__(256)
void k_flash(const unsigned short* __restrict__ QKV, const unsigned short* __restrict__ Vt,
             unsigned short* __restrict__ ctx) {
  // shorts: 4 slots x 8192 (K 4096 | V 4096 each)
  __shared__ __align__(16) unsigned short LDS[32768];
  const int tid = threadIdx.x, wid = tid >> 6, lane = tid & 63;
  const int l16 = lane & 15, krow = lane >> 4;
  const int bid = blockIdx.x;
  const int swz = (bid & 7) * 64 + (bid >> 3);    // 512 % 8 == 0 -> bijective
  const int head = swz >> 5, qb = swz & 31;       // 2 heads per XCD (K/V/Q ~3MB < 4MB L2)
  const float SC = 0.125f * 1.44269504089f;       // scale into log2 domain

  // Q fragments: lane holds q-row l16 (per mi), d = ks*32+krow*8..+7
  bf16x8 qf[2][2];
#pragma unroll
  for (int mi = 0; mi < 2; mi++)
#pragma unroll
    for (int ks = 0; ks < 2; ks++) {
      int row = qb * 128 + wid * 32 + mi * 16 + l16;
      qf[mi][ks] = *(const bf16x8*)&QKV[(size_t)row * 3072 + head * 64 + ks * 32 + krow * 8];
    }

  // hoisted LDS byte offsets (slot 0; slots via literal +16384k). V at koff+8192.
  unsigned koff[2][4];
#pragma unroll
  for (int ks = 0; ks < 2; ks++)
#pragma unroll
    for (int ni = 0; ni < 4; ni++) {
      int row = ni * 16 + l16;
      koff[ks][ni] = row * 128 + (((ks * 4 + krow) ^ (row & 7)) << 4);
    }

  // staging cursors: 256 threads stage 16 KB/tile in 2 passes (rows 0..31, 32..63);
  // pass-1 source = pass-0 + 32 rows (sch invariant: 32 = 0 mod 8), dest +4096 B.
  const unsigned short* kSrc;
  const unsigned short* vSrc;
  {
    int row = tid >> 3, sch = (tid & 7) ^ (row & 7);  // pre-swizzled source
    kSrc = QKV + (size_t)row * 3072 + 1024 + head * 64 + sch * 8;
    vSrc = Vt + (size_t)(head * 64 + row) * 4096 + sch * 8;
  }
  char* dK = (char*)LDS + wid * 1024;           // + lane*16 by HW
  char* dV = (char*)LDS + 8192 + wid * 1024;

  f32x4 oaccT[2][4] = {};   // O^T tiles [mi][di]; col=q(l16), row=d(krow*4+r)
  float mrun[2] = {-INFINITY, -INFINITY};
  float lrun[2] = {0.f, 0.f};   // PER-LANE partials (reduced in epilogue)

  auto stage = [&](const int B) {   // B = slot byte offset, literal; 4 loads
    gload_lds16(kSrc,             dK + B);
    gload_lds16(kSrc + 32 * 3072, dK + B + 4096);
    gload_lds16(vSrc,             dV + B);
    gload_lds16(vSrc + 32 * 4096, dV + B + 4096);
    kSrc += 64 * 3072;
    vSrc += 64;
  };

  auto body = [&](const int B) {  // B = slot byte offset, literal
    const char* L = (const char*)LDS;

    // swapped QK^T: sacc[mi][ni]; lane owns q=l16 (per mi), kv=ni*16+krow*4+r
    f32x4 sacc[2][4] = {};
    __builtin_amdgcn_s_setprio(1);
#pragma unroll
    for (int ks = 0; ks < 2; ks++)
#pragma unroll
      for (int ni = 0; ni < 4; ni++) {
        bf16x8 kf = *(const bf16x8*)(L + B + koff[ks][ni]);
#pragma unroll
        for (int mi = 0; mi < 2; mi++)
          sacc[mi][ni] = __builtin_amdgcn_mfma_f32_16x16x32_bf16(kf, qf[mi][ks], sacc[mi][ni], 0, 0, 0);
      }
    __builtin_amdgcn_s_setprio(0);

    // per-lane partial max over this lane's 16 kv values, per mi (raw domain)
    float pm[2];
#pragma unroll
    for (int mi = 0; mi < 2; mi++) {
      float a = fmax3(sacc[mi][0][0], sacc[mi][0][1], sacc[mi][0][2]);
      a = fmax3(a, sacc[mi][0][3], sacc[mi][1][0]);
      a = fmax3(a, sacc[mi][1][1], sacc[mi][1][2]);
      a = fmax3(a, sacc[mi][1][3], sacc[mi][2][0]);
      a = fmax3(a, sacc[mi][2][1], sacc[mi][2][2]);
      a = fmax3(a, sacc[mi][2][3], sacc[mi][3][0]);
      a = fmax3(a, sacc[mi][3][1], sacc[mi][3][2]);
      pm[mi] = fmaxf(a, sacc[mi][3][3]);
    }

    // defer-max: cross-lane reduce + rescale only on trigger
    if (__ballot((__builtin_fmaf(pm[0], SC, -mrun[0]) > 8.f) ||
                 (__builtin_fmaf(pm[1], SC, -mrun[1]) > 8.f))) {
#pragma unroll
      for (int mi = 0; mi < 2; mi++) {
        float a = pm[mi];
        a = fmaxf(a, __shfl_xor(a, 16));
        a = fmaxf(a, __shfl_xor(a, 32));      // uniform per q now
        float mnew = fmaxf(mrun[mi], a * SC);
        float al = __builtin_amdgcn_exp2f(mrun[mi] - mnew);  // per-lane q
        lrun[mi] *= al;
        mrun[mi] = mnew;
#pragma unroll
        for (int di = 0; di < 4; di++)
#pragma unroll
          for (int r = 0; r < 4; r++) oaccT[mi][di][r] *= al;
      }
    }

    // P = exp2(s*SC - m); per-lane partial row-sum (tree-reduced)
#pragma unroll
    for (int mi = 0; mi < 2; mi++) {
      float ps[4];
#pragma unroll
      for (int ni = 0; ni < 4; ni++) {
        float p0 = __builtin_amdgcn_exp2f(__builtin_fmaf(sacc[mi][ni][0], SC, -mrun[mi]));
        float p1 = __builtin_amdgcn_exp2f(__builtin_fmaf(sacc[mi][ni][1], SC, -mrun[mi]));
        float p2 = __builtin_amdgcn_exp2f(__builtin_fmaf(sacc[mi][ni][2], SC, -mrun[mi]));
        float p3 = __builtin_amdgcn_exp2f(__builtin_fmaf(sacc[mi][ni][3], SC, -mrun[mi]));
        sacc[mi][ni][0] = p0; sacc[mi][ni][1] = p1; sacc[mi][ni][2] = p2; sacc[mi][ni][3] = p3;
        ps[ni] = (p0 + p1) + (p2 + p3);
      }
      lrun[mi] += (ps[0] + ps[1]) + (ps[2] + ps[3]);
    }

    // B-frags: P^T packed from lane's OWN sacc under k-slot perm pi
    union PB { unsigned int w[4]; bf16x8 v; };
    PB pb[2][2];
#pragma unroll
    for (int mi = 0; mi < 2; mi++)
#pragma unroll
      for (int ks = 0; ks < 2; ks++) {
        pb[mi][ks].w[0] = pack_trunc(sacc[mi][2 * ks][0],     sacc[mi][2 * ks][1]);
        pb[mi][ks].w[1] = pack_trunc(sacc[mi][2 * ks][2],     sacc[mi][2 * ks][3]);
        pb[mi][ks].w[2] = pack_trunc(sacc[mi][2 * ks + 1][0], sacc[mi][2 * ks + 1][1]);
        pb[mi][ks].w[3] = pack_trunc(sacc[mi][2 * ks + 1][2], sacc[mi][2 * ks + 1][3]);
      }

    // O^T += V^T P^T: ONE b128 V-frag per (ks,di), SHARED across both mi tiles
    __builtin_amdgcn_s_setprio(1);
#pragma unroll
    for (int ks = 0; ks < 2; ks++)
#pragma unroll
      for (int di = 0; di < 4; di++) {
        bf16x8 av = *(const bf16x8*)(L + B + 8192 + koff[ks][di]);
#pragma unroll
        for (int mi = 0; mi < 2; mi++)
          oaccT[mi][di] = __builtin_amdgcn_mfma_f32_16x16x32_bf16(av, pb[mi][ks].v, oaccT[mi][di], 0, 0, 0);
      }
    __builtin_amdgcn_s_setprio(0);
  };

  // prologue: stage tiles 0,1,2 into slots 0,1,2 (12 loads in flight; cursor-ordered)
  stage(0);
  stage(16384);
  stage(32768);

  // steps t=0..59. Invariant at step t: tiles t,t+1,t+2 staged (12 outstanding;
  // t's 4 loads oldest). vmcnt(8) retires tile t.
  for (int t = 0; t < 60; t += 4) {
    FSYNC("8"); stage(49152); body(0);      // body t   (slot 0), stage t+3 (slot 3)
    FSYNC("8"); stage(0);     body(16384);  // body t+1 (slot 1), stage t+4 (slot 0)
    FSYNC("8"); stage(16384); body(32768);  // body t+2 (slot 2), stage t+5 (slot 1)
    FSYNC("8"); stage(32768); body(49152);  // body t+3 (slot 3), stage t+6 (slot 2)
  }
  // tail: stage tile 63 at t=60; drain 8 -> 8 -> 4 -> 0
  FSYNC("8"); stage(49152); body(0);        // t=60 (slot 0), stage 63 (slot 3)
  FSYNC("8"); body(16384);                  // t=61 (slot 1)
  FSYNC("4"); body(32768);                  // t=62 (slot 2)
  FSYNC("0"); body(49152);                  // t=63 (slot 3)

  // epilogue: reduce per-lane l partials, per-lane normalize, 8B packed stores
#pragma unroll
  for (int mi = 0; mi < 2; mi++) {
    float lr = lrun[mi];
    lr += __shfl_xor(lr, 16);
    lr += __shfl_xor(lr, 32);
    float li = 1.0f / lr;
    int row = qb * 128 + wid * 32 + mi * 16 + l16;
#pragma unroll
    for (int di = 0; di < 4; di++) {
      uint2 w;
      w.x = (unsigned)f2bf(oaccT[mi][di][0] * li) | ((unsigned)f2bf(oaccT[mi][di][1] * li) << 16);
      w.y = (unsigned)f2bf(oaccT[mi][di][2] * li) | ((unsigned)f2bf(oaccT[mi][di][3] * li) << 16);
      *(uint2*)&ctx[(size_t)row * 1024 + head * 64 + di * 16 + krow * 4] = w;
    }
  }
}

// ---------- LN(x + proj_bf16) -> bf16 only ----------
__global__ __launch_bounds__(256)
void k_ln_res(const float* __restrict__ base, const unsigned short* __restrict__ add,
              const float* __restrict__ g, const float* __restrict__ bb,
              unsigned short* __restrict__ outb) {
  const int r = blockIdx.x, tid = threadIdx.x;
  float4 v = ((const float4*)(base + (size_t)r * 1024))[tid];
  {
    u16x4 w = ((const u16x4*)(add + (size_t)r * 1024))[tid];
    v.x += bf2f(w.x); v.y += bf2f(w.y); v.z += bf2f(w.z); v.w += bf2f(w.w);
  }
  float s1 = v.x + v.y + v.z + v.w;
  float s2 = v.x * v.x + v.y * v.y + v.z * v.z + v.w * v.w;
#pragma unroll
  for (int off = 32; off >= 1; off >>= 1) { s1 += __shfl_xor(s1, off); s2 += __shfl_xor(s2, off); }
  __shared__ float red[8];
  if ((tid & 63) == 0) { red[tid >> 6] = s1; red[4 + (tid >> 6)] = s2; }
  __syncthreads();
  s1 = red[0] + red[1] + red[2] + red[3];
  s2 = red[4] + red[5] + red[6] + red[7];
  const float mu = s1 * (1.0f / 1024.0f);
  const float var = s2 * (1.0f / 1024.0f) - mu * mu;
  const float rs = rsqrtf(var + 1e-5f);
  float4 gv = ((const float4*)g)[tid];
  float4 bv = ((const float4*)bb)[tid];
  u16x4 o;
  o.x = f2bf((v.x - mu) * rs * gv.x + bv.x);
  o.y = f2bf((v.y - mu) * rs * gv.y + bv.y);
  o.z = f2bf((v.z - mu) * rs * gv.z + bv.z);
  o.w = f2bf((v.w - mu) * rs * gv.w + bv.w);
  ((u16x4*)(outb + (size_t)r * 1024))[tid] = o;
}

// ---------- relu(LN(lin_bf16 + out_b + mha_bf16)) -> fp32 out ----------
__global__ __launch_bounds__(256)
void k_ln2(const unsigned short* __restrict__ lin, const unsigned short* __restrict__ mha,
           const float* __restrict__ ob, const float* __restrict__ g,
           const float* __restrict__ bb, float* __restrict__ out) {
  const int r = blockIdx.x, tid = threadIdx.x;
  float4 v;
  {
    u16x4 a = ((const u16x4*)(lin + (size_t)r * 1024))[tid];
    u16x4 w = ((const u16x4*)(mha + (size_t)r * 1024))[tid];
    float4 o = ((const float4*)ob)[tid];
    v.x = bf2f(a.x) + bf2f(w.x) + o.x;
    v.y = bf2f(a.y) + bf2f(w.y) + o.y;
    v.z = bf2f(a.z) + bf2f(w.z) + o.z;
    v.w = bf2f(a.w) + bf2f(w.w) + o.w;
  }
  float s1 = v.x + v.y + v.z + v.w;
  float s2 = v.x * v.x + v.y * v.y + v.z * v.z + v.w * v.w;
#pragma unroll
  for (int off = 32; off >= 1; off >>= 1) { s1 += __shfl_xor(s1, off); s2 += __shfl_xor(s2, off); }
  __shared__ float red[8];
  if ((tid & 63) == 0) { red[tid >> 6] = s1; red[4 + (tid >> 6)] = s2; }
  __syncthreads();
  s1 = red[0] + red[1] + red[2] + red[3];
  s2 = red[4] + red[5] + red[6] + red[7];
  const float mu = s1 * (1.0f / 1024.0f);
  const float var = s2 * (1.0f / 1024.0f) - mu * mu;
  const float rs = rsqrtf(var + 1e-5f);
  float4 gv = ((const float4*)g)[tid];
  float4 bv = ((const float4*)bb)[tid];
  float4 y;
  y.x = fmaxf(0.f, (v.x - mu) * rs * gv.x + bv.x);
  y.y = fmaxf(0.f, (v.y - mu) * rs * gv.y + bv.y);
  y.z = fmaxf(0.f, (v.z - mu) * rs * gv.z + bv.z);
  y.w = fmaxf(0.f, (v.w - mu) * rs * gv.w + bv.w);
  ((float4*)(out + (size_t)r * 1024))[tid] = y;
}

// ---------- launch ----------
extern "C" void kernel_launch(void* const* d_in, const int* in_sizes, int n_in,
                              void* d_out, int out_size, void* d_ws, size_t ws_size,
                              hipStream_t stream) {
  (void)in_sizes; (void)n_in; (void)out_size; (void)ws_size;
  const float* x     = (const float*)d_in[0];
  const float* Wq    = (const float*)d_in[1];
  const float* Wk    = (const float*)d_in[2];
  const float* Wv    = (const float*)d_in[3];
  const float* Wo    = (const float*)d_in[4];
  const float* out_w = (const float*)d_in[5];
  const float* out_b = (const float*)d_in[6];
  const float* g1    = (const float*)d_in[7];
  const float* b1    = (const float*)d_in[8];
  const float* g2    = (const float*)d_in[9];
  const float* b2    = (const float*)d_in[10];
  float* out = (float*)d_out;

  // workspace layout (aliased; 60 MB total, liveness-checked)
  const size_t MB = 1ull << 20;
  char* ws = (char*)d_ws;
  unsigned short* xb    = (unsigned short*)(ws + 0);        // [4096][1024] bf16   (dead after GEMM1)
  unsigned short* WqkvT = (unsigned short*)(ws + 8 * MB);   // [3072][1024] bf16   (dead after GEMM1)
  unsigned short* OwB   = (unsigned short*)(ws + 16 * MB);  // out_w bf16 [1024][1024]
  unsigned short* QKV   = (unsigned short*)(ws + 18 * MB);  // [4096][3072] bf16 (Q,K used; V cols unwritten)
  unsigned short* Vt    = (unsigned short*)(ws + 42 * MB);  // [1024][4096] bf16 kv-permuted (dead after attn)
  unsigned short* ctx   = (unsigned short*)(ws + 50 * MB);  // [4096][1024] bf16   (dead after GEMM2)
  unsigned short* WoT   = (unsigned short*)(ws + 58 * MB);  // W_o^T bf16
  unsigned short* proj  = (unsigned short*)(ws + 0);        // [4096][1024] bf16 (over xb)
  unsigned short* mhaB  = (unsigned short*)(ws + 34 * MB);  // [4096][1024] bf16 (over QKV tail)
  unsigned short* lin   = (unsigned short*)(ws + 42 * MB);  // [4096][1024] bf16 (over Vt)

  k_prep<<<9216, 256, 0, stream>>>(x, xb, out_w, OwB, Wq, Wk, Wv, Wo, WqkvT, WoT);

  // GEMM1: QKV projection; V columns (n0>=2048) stream transposed+permuted into Vt
  k_gemm_bt<2><<<dim3(32, 24), 256, 0, stream>>>(xb, WqkvT, QKV, Vt, 4096, 3072, 1024);
  k_flash<<<512, 256, 0, stream>>>(QKV, Vt, ctx);
  k_gemm_bt_n64<1><<<dim3(32, 16), 256, 0, stream>>>(ctx, WoT, proj, 4096, 1024, 1024);
  k_ln_res<<<4096, 256, 0, stream>>>(x, proj, g1, b1, mhaB);
  k_gemm_bt_n64<1><<<dim3(32, 16), 256, 0, stream>>>(mhaB, OwB, lin, 4096, 1024, 1024);
  k_ln2<<<4096, 256, 0, stream>>>(lin, mhaB, out_b, g2, b2, out);
}

// Round 19
// 179.795 us; speedup vs baseline: 1.0165x; 1.0165x over previous
//
#include <hip/hip_runtime.h>
#include <cstdint>
#include <math.h>

// ---------- types ----------
typedef __attribute__((ext_vector_type(8))) short bf16x8;   // MFMA A/B operand (4 VGPRs)
typedef __attribute__((ext_vector_type(4))) float f32x4;    // MFMA C/D operand
typedef __attribute__((ext_vector_type(4))) unsigned short u16x4;

__device__ __forceinline__ unsigned short f2bf(float f) {
  union { float f; unsigned int u; } c; c.f = f;
  unsigned int u = c.u;
  return (unsigned short)((u + 0x7FFFu + ((u >> 16) & 1u)) >> 16);  // RNE
}
__device__ __forceinline__ float bf2f(unsigned short u) {
  return __uint_as_float(((unsigned int)u) << 16);
}

// pack hi16(a) | hi16(b)<<16 via v_perm_b32 (1 VALU op; trunc-to-bf16)
__device__ __forceinline__ unsigned int pack_trunc(float a, float b) {
  return __builtin_amdgcn_perm(__float_as_uint(b), __float_as_uint(a), 0x07060302u);
}

__device__ __forceinline__ float fmax3(float a, float b, float c) {
  return fmaxf(fmaxf(a, b), c);  // clang fuses to v_max3_f32
}

__device__ __forceinline__ void gload_lds16(const void* g, void* l) {
  __builtin_amdgcn_global_load_lds(
      (const __attribute__((address_space(1))) unsigned int*)g,
      (__attribute__((address_space(3))) unsigned int*)l, 16, 0, 0);
}

// counted-vmcnt barrier (T4): wait only the oldest loads, never full drain
#define FSYNC(N) do {                                        \
    asm volatile("s_waitcnt vmcnt(" N ")" ::: "memory");     \
    __builtin_amdgcn_s_barrier();                            \
    __builtin_amdgcn_sched_barrier(0);                       \
  } while (0)

// ---------- prep: weight transposes (blocks 0..4095) + fp32->bf16 converts ----------
__global__ __launch_bounds__(256)
void k_prep(const float* __restrict__ x, unsigned short* __restrict__ xb,
            const float* __restrict__ out_w, unsigned short* __restrict__ OwB,
            const float* __restrict__ w0, const float* __restrict__ w1,
            const float* __restrict__ w2, const float* __restrict__ w3,
            unsigned short* __restrict__ o012, unsigned short* __restrict__ o3) {
  __shared__ float t[32][33];
  const int b = blockIdx.x;
  if (b < 4096) {
    const int m = b >> 10, rem = b & 1023;
    const float* in = m == 0 ? w0 : m == 1 ? w1 : m == 2 ? w2 : w3;
    unsigned short* out = m < 3 ? o012 + (size_t)m * 1048576 : o3;
    const int r0 = (rem >> 5) << 5, c0 = (rem & 31) << 5;
    const int tx = threadIdx.x & 31, ty = threadIdx.x >> 5;  // 32 x 8
#pragma unroll
    for (int rr = ty; rr < 32; rr += 8) t[rr][tx] = in[(size_t)(r0 + rr) * 1024 + c0 + tx];
    __syncthreads();
#pragma unroll
    for (int cc = ty; cc < 32; cc += 8)
      out[(size_t)(c0 + cc) * 1024 + r0 + tx] = f2bf(t[tx][cc]);
  } else {
    int i = (b - 4096) * 256 + threadIdx.x;
    const float* in;
    unsigned short* out;
    if (i < 1048576) { in = x; out = xb; }
    else { i -= 1048576; if (i >= 262144) return; in = out_w; out = OwB; }
    float4 v = ((const float4*)in)[i];
    u16x4 o;
    o.x = f2bf(v.x); o.y = f2bf(v.y); o.z = f2bf(v.z); o.w = f2bf(v.w);
    ((u16x4*)out)[i] = o;
  }
}

// ---------- bf16 GEMM 128x128, dbuf + 1 barrier/K-step (T3-min) ----------
// MODE 0: fp32 C.  MODE 1: bf16 C.  MODE 2: bf16 C for n0<VCOL0; cols >= VCOL0
// are written TRANSPOSED to VT[col-VCOL0][rowPerm] (fused V-transpose, with the
// per-64-tile kv permutation so flash PV reads are single b128 under perm pi).
template <int MODE>
__global__ __launch_bounds__(256)
void k_gemm_bt(const unsigned short* __restrict__ A, const unsigned short* __restrict__ BT,
               void* __restrict__ C, unsigned short* __restrict__ VT,
               int M, int N, int K) {
  const int VCOL0 = 2048;
  __shared__ __align__(16) unsigned short As[2][128 * 32];
  __shared__ __align__(16) unsigned short Bs[2][128 * 32];
  const int tid = threadIdx.x;
  const int wid = tid >> 6, lane = tid & 63;
  const int l16 = lane & 15, krow = lane >> 4;
  const int m0 = blockIdx.x * 128, n0 = blockIdx.y * 128;
  const int wr = wid >> 1, wc = wid & 1;  // 2x2 waves, 64x64 each

  f32x4 acc[4][4] = {};

  auto stageG = [&](int buf, int k0) {
#pragma unroll
    for (int j = 0; j < 2; j++) {
      int f = j * 256 + tid;
      gload_lds16(A  + (size_t)(m0 + (f >> 2)) * K + k0 + (f & 3) * 8,
                  (char*)As[buf] + (size_t)(j * 256 + wid * 64) * 16);
      gload_lds16(BT + (size_t)(n0 + (f >> 2)) * K + k0 + (f & 3) * 8,
                  (char*)Bs[buf] + (size_t)(j * 256 + wid * 64) * 16);
    }
  };
  auto comp = [&](int buf) {
    bf16x8 a[4], b[4];
#pragma unroll
    for (int i = 0; i < 4; i++) {
      a[i] = *(const bf16x8*)&As[buf][(wr * 64 + i * 16 + l16) * 32 + krow * 8];
      b[i] = *(const bf16x8*)&Bs[buf][(wc * 64 + i * 16 + l16) * 32 + krow * 8];
    }
#pragma unroll
    for (int mi = 0; mi < 4; mi++)
#pragma unroll
      for (int ni = 0; ni < 4; ni++)
        acc[mi][ni] = __builtin_amdgcn_mfma_f32_16x16x32_bf16(a[mi], b[ni], acc[mi][ni], 0, 0, 0);
  };

  stageG(0, 0);
  __syncthreads();
  for (int k0 = 0; k0 < K; k0 += 64) {
    if (k0 + 32 < K) stageG(1, k0 + 32);
    comp(0);
    __syncthreads();
    if (k0 + 64 < K) stageG(0, k0 + 64);
    comp(1);
    __syncthreads();
  }

  if (MODE == 2 && n0 >= VCOL0) {
    // V region: write transposed to VT[col - VCOL0][rowPerm]; rows consecutive per
    // lane (r=0..3) stay contiguous under the kv permutation (r bits unchanged).
#pragma unroll
    for (int mi = 0; mi < 4; mi++)
#pragma unroll
      for (int ni = 0; ni < 4; ni++) {
        int col = n0 - VCOL0 + wc * 64 + ni * 16 + l16;
        int row = m0 + wr * 64 + mi * 16 + krow * 4;
        int u0 = row & 63;
        int rowp = (row & ~63) | (u0 & 32) | ((u0 & 12) << 1) | (((u0 >> 4) & 1) << 2);
        uint2 w;
        w.x = (unsigned)f2bf(acc[mi][ni][0]) | ((unsigned)f2bf(acc[mi][ni][1]) << 16);
        w.y = (unsigned)f2bf(acc[mi][ni][2]) | ((unsigned)f2bf(acc[mi][ni][3]) << 16);
        *(uint2*)&VT[(size_t)col * 4096 + rowp] = w;
      }
    return;
  }

#pragma unroll
  for (int mi = 0; mi < 4; mi++)
#pragma unroll
    for (int ni = 0; ni < 4; ni++)
#pragma unroll
      for (int r = 0; r < 4; r++) {
        int row = m0 + wr * 64 + mi * 16 + krow * 4 + r;
        int col = n0 + wc * 64 + ni * 16 + l16;
        float v = acc[mi][ni][r];
        if (MODE) ((unsigned short*)C)[(size_t)row * N + col] = f2bf(v);
        else      ((float*)C)[(size_t)row * N + col] = v;
      }
}

// ---------- bf16 GEMM 128x64, dbuf + 1 barrier/K-step ----------
template <int OUTBF>
__global__ __launch_bounds__(256)
void k_gemm_bt_n64(const unsigned short* __restrict__ A, const unsigned short* __restrict__ BT,
                   void* __restrict__ C, int M, int N, int K) {
  __shared__ __align__(16) unsigned short As[2][128 * 32];
  __shared__ __align__(16) unsigned short Bs[2][64 * 32];
  const int tid = threadIdx.x;
  const int wid = tid >> 6, lane = tid & 63;
  const int l16 = lane & 15, krow = lane >> 4;
  const int m0 = blockIdx.x * 128, n0 = blockIdx.y * 64;
  const int wr = wid >> 1, wc = wid & 1;  // 2x2 waves, 64x32 each

  f32x4 acc[4][2] = {};

  auto stageG = [&](int buf, int k0) {
#pragma unroll
    for (int j = 0; j < 2; j++) {
      int f = j * 256 + tid;
      gload_lds16(A + (size_t)(m0 + (f >> 2)) * K + k0 + (f & 3) * 8,
                  (char*)As[buf] + (size_t)(j * 256 + wid * 64) * 16);
    }
    gload_lds16(BT + (size_t)(n0 + (tid >> 2)) * K + k0 + (tid & 3) * 8,
                (char*)Bs[buf] + (size_t)(wid * 64) * 16);
  };
  auto comp = [&](int buf) {
    bf16x8 a[4], b[2];
#pragma unroll
    for (int i = 0; i < 4; i++)
      a[i] = *(const bf16x8*)&As[buf][(wr * 64 + i * 16 + l16) * 32 + krow * 8];
#pragma unroll
    for (int i = 0; i < 2; i++)
      b[i] = *(const bf16x8*)&Bs[buf][(wc * 32 + i * 16 + l16) * 32 + krow * 8];
#pragma unroll
    for (int mi = 0; mi < 4; mi++)
#pragma unroll
      for (int ni = 0; ni < 2; ni++)
        acc[mi][ni] = __builtin_amdgcn_mfma_f32_16x16x32_bf16(a[mi], b[ni], acc[mi][ni], 0, 0, 0);
  };

  stageG(0, 0);
  __syncthreads();
  for (int k0 = 0; k0 < K; k0 += 64) {
    if (k0 + 32 < K) stageG(1, k0 + 32);
    comp(0);
    __syncthreads();
    if (k0 + 64 < K) stageG(0, k0 + 64);
    comp(1);
    __syncthreads();
  }

#pragma unroll
  for (int mi = 0; mi < 4; mi++)
#pragma unroll
    for (int ni = 0; ni < 2; ni++)
#pragma unroll
      for (int r = 0; r < 4; r++) {
        int row = m0 + wr * 64 + mi * 16 + krow * 4 + r;
        int col = n0 + wc * 32 + ni * 16 + l16;
        float v = acc[mi][ni][r];
        if (OUTBF) ((unsigned short*)C)[(size_t)row * N + col] = f2bf(v);
        else       ((float*)C)[(size_t)row * N + col] = v;
      }
}

// ---------- flash attention (R17: best measured — Q=16, pipeline, b128 PV) ----------
// 8 waves/WG (512 thr), 128 q-rows/WG, 16 q-rows/wave, grid 512 (16 heads x 32 qb).
// LDS 64 KB: 4 slots x (K 8KB | V 8KB) -> 2 WG/CU = 16 waves/CU. Prefetch depth 3,
// counted vmcnt(4) barriers (T4). Vt is kv-permuted by GEMM1 so the PV V A-frag
// is a SINGLE ds_read_b128 at koff+8192 (same address form as the K reads).
__global__ __launch_bounds__(512)
void k_flash(const unsigned short* __restrict__ QKV, const unsigned short* __restrict__ Vt,
             unsigned short* __restrict__ ctx) {
  // shorts: 4 slots x 8192 (K 4096 | V 4096 each)
  __shared__ __align__(16) unsigned short LDS[32768];
  const int tid = threadIdx.x, wid = tid >> 6, lane = tid & 63;
  const int l16 = lane & 15, krow = lane >> 4;
  const int bid = blockIdx.x;
  const int swz = (bid & 7) * 64 + (bid >> 3);    // 512 % 8 == 0 -> bijective
  const int head = swz >> 5, qb = swz & 31;       // 2 heads per XCD (K/V/Q ~3MB < 4MB L2)
  const float SC = 0.125f * 1.44269504089f;       // scale into log2 domain

  // Q fragments (B-operand of swapped QK^T): lane holds q-row l16, d = ks*32+krow*8..+7
  bf16x8 qf[2];
#pragma unroll
  for (int ks = 0; ks < 2; ks++) {
    int row = qb * 128 + wid * 16 + l16;
    qf[ks] = *(const bf16x8*)&QKV[(size_t)row * 3072 + head * 64 + ks * 32 + krow * 8];
  }

  // hoisted LDS byte offsets (slot 0; other slots via literal +16384k).
  // V reads use koff + 8192 (identical address form; Vt pre-permuted).
  unsigned koff[2][4];
#pragma unroll
  for (int ks = 0; ks < 2; ks++)
#pragma unroll
    for (int ni = 0; ni < 4; ni++) {
      int row = ni * 16 + l16;
      koff[ks][ni] = row * 128 + (((ks * 4 + krow) ^ (row & 7)) << 4);
    }

  // staging source cursors (advance once per staged tile) + fixed LDS dests
  const unsigned short* kSrc;
  const unsigned short* vSrc;
  {
    int row = tid >> 3, sch = (tid & 7) ^ (row & 7);  // pre-swizzled source
    kSrc = QKV + (size_t)row * 3072 + 1024 + head * 64 + sch * 8;
    vSrc = Vt + (size_t)(head * 64 + row) * 4096 + sch * 8;
  }
  char* dK = (char*)LDS + wid * 1024;           // + lane*16 by HW
  char* dV = (char*)LDS + 8192 + wid * 1024;

  f32x4 oaccT[4] = {};      // O^T tiles [di]; col=q(l16), row=d(krow*4+r)
  float mrun = -INFINITY;   // uniform across the 4 krow-lanes of a q
  float lrun = 0.f;         // PER-LANE partial (reduced in epilogue)

  auto stage = [&](const int B) {   // B = slot byte offset, literal
    gload_lds16(kSrc, dK + B);
    gload_lds16(vSrc, dV + B);
    kSrc += 64 * 3072;
    vSrc += 64;
  };

  auto body = [&](const int B) {  // B = slot byte offset, literal
    const char* L = (const char*)LDS;

    // swapped QK^T: sacc[ni] = S^T tile [kv 16][q 16]; lane owns q=l16, kv=ni*16+krow*4+r
    f32x4 sacc[4] = {};
    __builtin_amdgcn_s_setprio(1);
#pragma unroll
    for (int ks = 0; ks < 2; ks++)
#pragma unroll
      for (int ni = 0; ni < 4; ni++) {
        bf16x8 kf = *(const bf16x8*)(L + B + koff[ks][ni]);
        sacc[ni] = __builtin_amdgcn_mfma_f32_16x16x32_bf16(kf, qf[ks], sacc[ni], 0, 0, 0);
      }
    __builtin_amdgcn_s_setprio(0);

    // per-lane partial max over this lane's 16 kv values (raw domain)
    float a = fmax3(sacc[0][0], sacc[0][1], sacc[0][2]);
    a = fmax3(a, sacc[0][3], sacc[1][0]);
    a = fmax3(a, sacc[1][1], sacc[1][2]);
    a = fmax3(a, sacc[1][3], sacc[2][0]);
    a = fmax3(a, sacc[2][1], sacc[2][2]);
    a = fmax3(a, sacc[2][3], sacc[3][0]);
    a = fmax3(a, sacc[3][1], sacc[3][2]);
    a = fmaxf(a, sacc[3][3]);

    // defer-max: cross-lane reduce + rescale only when some lane's partial
    // exceeds the running max by > 8 (log2 domain)
    if (__ballot(__builtin_fmaf(a, SC, -mrun) > 8.f)) {
      a = fmaxf(a, __shfl_xor(a, 16));
      a = fmaxf(a, __shfl_xor(a, 32));      // uniform per q now
      float mnew = fmaxf(mrun, a * SC);
      float al = __builtin_amdgcn_exp2f(mrun - mnew);
      lrun *= al;
      mrun = mnew;
#pragma unroll
      for (int di = 0; di < 4; di++)
#pragma unroll
        for (int r = 0; r < 4; r++) oaccT[di][r] *= al;
    }

    // P = exp2(s*SC - m); per-lane partial row-sum (tree-reduced add chain)
    float ps[4];
#pragma unroll
    for (int ni = 0; ni < 4; ni++) {
      float p0 = __builtin_amdgcn_exp2f(__builtin_fmaf(sacc[ni][0], SC, -mrun));
      float p1 = __builtin_amdgcn_exp2f(__builtin_fmaf(sacc[ni][1], SC, -mrun));
      float p2 = __builtin_amdgcn_exp2f(__builtin_fmaf(sacc[ni][2], SC, -mrun));
      float p3 = __builtin_amdgcn_exp2f(__builtin_fmaf(sacc[ni][3], SC, -mrun));
      sacc[ni][0] = p0; sacc[ni][1] = p1; sacc[ni][2] = p2; sacc[ni][3] = p3;
      ps[ni] = (p0 + p1) + (p2 + p3);
    }
    lrun += (ps[0] + ps[1]) + (ps[2] + ps[3]);

    // B-frags: P^T packed from this lane's OWN sacc under k-slot perm pi:
    //   pi(ks,krow,j) = (2ks + (j>>2))*16 + krow*4 + (j&3)
    union PB { unsigned int w[4]; bf16x8 v; };
    PB pb[2];
#pragma unroll
    for (int ks = 0; ks < 2; ks++) {
      pb[ks].w[0] = pack_trunc(sacc[2 * ks][0],     sacc[2 * ks][1]);
      pb[ks].w[1] = pack_trunc(sacc[2 * ks][2],     sacc[2 * ks][3]);
      pb[ks].w[2] = pack_trunc(sacc[2 * ks + 1][0], sacc[2 * ks + 1][1]);
      pb[ks].w[3] = pack_trunc(sacc[2 * ks + 1][2], sacc[2 * ks + 1][3]);
    }

    // O^T += V^T P^T: A-frag = ONE b128 (Vt pre-permuted; same pi as pb)
    __builtin_amdgcn_s_setprio(1);
#pragma unroll
    for (int ks = 0; ks < 2; ks++)
#pragma unroll
      for (int di = 0; di < 4; di++) {
        bf16x8 av = *(const bf16x8*)(L + B + 8192 + koff[ks][di]);
        oaccT[di] = __builtin_amdgcn_mfma_f32_16x16x32_bf16(av, pb[ks].v, oaccT[di], 0, 0, 0);
      }
    __builtin_amdgcn_s_setprio(0);
  };

  // prologue: stage tiles 0,1,2 into slots 0,1,2 (6 loads in flight; cursor-ordered)
  stage(0);
  stage(16384);
  stage(32768);

  // steps t=0..59 (15 x 4 unroll, literal slots). Invariant at step t: tiles
  // t,t+1,t+2 staged (6 outstanding; t's 2 loads oldest). vmcnt(4) retires t.
  for (int t = 0; t < 60; t += 4) {
    FSYNC("4"); stage(49152); body(0);      // body tile t   (slot 0), stage t+3 (slot 3)
    FSYNC("4"); stage(0);     body(16384);  // body tile t+1 (slot 1), stage t+4 (slot 0)
    FSYNC("4"); stage(16384); body(32768);  // body tile t+2 (slot 2), stage t+5 (slot 1)
    FSYNC("4"); stage(32768); body(49152);  // body tile t+3 (slot 3), stage t+6 (slot 2)
  }
  // tail t=60..63: stage tile 63 at t=60; drain 4 -> 4 -> 2 -> 0
  FSYNC("4"); stage(49152); body(0);        // t=60 (slot 0), stage 63 (slot 3)
  FSYNC("4"); body(16384);                  // t=61 (slot 1)
  FSYNC("2"); body(32768);                  // t=62 (slot 2)
  FSYNC("0"); body(49152);                  // t=63 (slot 3)

  // epilogue: reduce per-lane l partials across the 4 krow-lanes of each q,
  // then per-lane normalize + 8B packed stores
  float lr = lrun;
  lr += __shfl_xor(lr, 16);
  lr += __shfl_xor(lr, 32);
  float li = 1.0f / lr;
  int row = qb * 128 + wid * 16 + l16;
#pragma unroll
  for (int di = 0; di < 4; di++) {
    uint2 w;
    w.x = (unsigned)f2bf(oaccT[di][0] * li) | ((unsigned)f2bf(oaccT[di][1] * li) << 16);
    w.y = (unsigned)f2bf(oaccT[di][2] * li) | ((unsigned)f2bf(oaccT[di][3] * li) << 16);
    *(uint2*)&ctx[(size_t)row * 1024 + head * 64 + di * 16 + krow * 4] = w;
  }
}

// ---------- LN(x + proj_bf16) -> bf16 only ----------
__global__ __launch_bounds__(256)
void k_ln_res(const float* __restrict__ base, const unsigned short* __restrict__ add,
              const float* __restrict__ g, const float* __restrict__ bb,
              unsigned short* __restrict__ outb) {
  const int r = blockIdx.x, tid = threadIdx.x;
  float4 v = ((const float4*)(base + (size_t)r * 1024))[tid];
  {
    u16x4 w = ((const u16x4*)(add + (size_t)r * 1024))[tid];
    v.x += bf2f(w.x); v.y += bf2f(w.y); v.z += bf2f(w.z); v.w += bf2f(w.w);
  }
  float s1 = v.x + v.y + v.z + v.w;
  float s2 = v.x * v.x + v.y * v.y + v.z * v.z + v.w * v.w;
#pragma unroll
  for (int off = 32; off >= 1; off >>= 1) { s1 += __shfl_xor(s1, off); s2 += __shfl_xor(s2, off); }
  __shared__ float red[8];
  if ((tid & 63) == 0) { red[tid >> 6] = s1; red[4 + (tid >> 6)] = s2; }
  __syncthreads();
  s1 = red[0] + red[1] + red[2] + red[3];
  s2 = red[4] + red[5] + red[6] + red[7];
  const float mu = s1 * (1.0f / 1024.0f);
  const float var = s2 * (1.0f / 1024.0f) - mu * mu;
  const float rs = rsqrtf(var + 1e-5f);
  float4 gv = ((const float4*)g)[tid];
  float4 bv = ((const float4*)bb)[tid];
  u16x4 o;
  o.x = f2bf((v.x - mu) * rs * gv.x + bv.x);
  o.y = f2bf((v.y - mu) * rs * gv.y + bv.y);
  o.z = f2bf((v.z - mu) * rs * gv.z + bv.z);
  o.w = f2bf((v.w - mu) * rs * gv.w + bv.w);
  ((u16x4*)(outb + (size_t)r * 1024))[tid] = o;
}

// ---------- relu(LN(lin_bf16 + out_b + mha_bf16)) -> fp32 out ----------
__global__ __launch_bounds__(256)
void k_ln2(const unsigned short* __restrict__ lin, const unsigned short* __restrict__ mha,
           const float* __restrict__ ob, const float* __restrict__ g,
           const float* __restrict__ bb, float* __restrict__ out) {
  const int r = blockIdx.x, tid = threadIdx.x;
  float4 v;
  {
    u16x4 a = ((const u16x4*)(lin + (size_t)r * 1024))[tid];
    u16x4 w = ((const u16x4*)(mha + (size_t)r * 1024))[tid];
    float4 o = ((const float4*)ob)[tid];
    v.x = bf2f(a.x) + bf2f(w.x) + o.x;
    v.y = bf2f(a.y) + bf2f(w.y) + o.y;
    v.z = bf2f(a.z) + bf2f(w.z) + o.z;
    v.w = bf2f(a.w) + bf2f(w.w) + o.w;
  }
  float s1 = v.x + v.y + v.z + v.w;
  float s2 = v.x * v.x + v.y * v.y + v.z * v.z + v.w * v.w;
#pragma unroll
  for (int off = 32; off >= 1; off >>= 1) { s1 += __shfl_xor(s1, off); s2 += __shfl_xor(s2, off); }
  __shared__ float red[8];
  if ((tid & 63) == 0) { red[tid >> 6] = s1; red[4 + (tid >> 6)] = s2; }
  __syncthreads();
  s1 = red[0] + red[1] + red[2] + red[3];
  s2 = red[4] + red[5] + red[6] + red[7];
  const float mu = s1 * (1.0f / 1024.0f);
  const float var = s2 * (1.0f / 1024.0f) - mu * mu;
  const float rs = rsqrtf(var + 1e-5f);
  float4 gv = ((const float4*)g)[tid];
  float4 bv = ((const float4*)bb)[tid];
  float4 y;
  y.x = fmaxf(0.f, (v.x - mu) * rs * gv.x + bv.x);
  y.y = fmaxf(0.f, (v.y - mu) * rs * gv.y + bv.y);
  y.z = fmaxf(0.f, (v.z - mu) * rs * gv.z + bv.z);
  y.w = fmaxf(0.f, (v.w - mu) * rs * gv.w + bv.w);
  ((float4*)(out + (size_t)r * 1024))[tid] = y;
}

// ---------- launch ----------
extern "C" void kernel_launch(void* const* d_in, const int* in_sizes, int n_in,
                              void* d_out, int out_size, void* d_ws, size_t ws_size,
                              hipStream_t stream) {
  (void)in_sizes; (void)n_in; (void)out_size; (void)ws_size;
  const float* x     = (const float*)d_in[0];
  const float* Wq    = (const float*)d_in[1];
  const float* Wk    = (const float*)d_in[2];
  const float* Wv    = (const float*)d_in[3];
  const float* Wo    = (const float*)d_in[4];
  const float* out_w = (const float*)d_in[5];
  const float* out_b = (const float*)d_in[6];
  const float* g1    = (const float*)d_in[7];
  const float* b1    = (const float*)d_in[8];
  const float* g2    = (const float*)d_in[9];
  const float* b2    = (const float*)d_in[10];
  float* out = (float*)d_out;

  // workspace layout (aliased; 60 MB total, liveness-checked)
  const size_t MB = 1ull << 20;
  char* ws = (char*)d_ws;
  unsigned short* xb    = (unsigned short*)(ws + 0);        // [4096][1024] bf16   (dead after GEMM1)
  unsigned short* WqkvT = (unsigned short*)(ws + 8 * MB);   // [3072][1024] bf16   (dead after GEMM1)
  unsigned short* OwB   = (unsigned short*)(ws + 16 * MB);  // out_w bf16 [1024][1024]
  unsigned short* QKV   = (unsigned short*)(ws + 18 * MB);  // [4096][3072] bf16 (Q,K used; V cols unwritten)
  unsigned short* Vt    = (unsigned short*)(ws + 42 * MB);  // [1024][4096] bf16 kv-permuted (dead after attn)
  unsigned short* ctx   = (unsigned short*)(ws + 50 * MB);  // [4096][1024] bf16   (dead after GEMM2)
  unsigned short* WoT   = (unsigned short*)(ws + 58 * MB);  // W_o^T bf16
  unsigned short* proj  = (unsigned short*)(ws + 0);        // [4096][1024] bf16 (over xb)
  unsigned short* mhaB  = (unsigned short*)(ws + 34 * MB);  // [4096][1024] bf16 (over QKV tail)
  unsigned short* lin   = (unsigned short*)(ws + 42 * MB);  // [4096][1024] bf16 (over Vt)

  k_prep<<<9216, 256, 0, stream>>>(x, xb, out_w, OwB, Wq, Wk, Wv, Wo, WqkvT, WoT);

  // GEMM1: QKV projection; V columns (n0>=2048) stream transposed+permuted into Vt
  k_gemm_bt<2><<<dim3(32, 24), 256, 0, stream>>>(xb, WqkvT, QKV, Vt, 4096, 3072, 1024);
  k_flash<<<512, 512, 0, stream>>>(QKV, Vt, ctx);
  k_gemm_bt_n64<1><<<dim3(32, 16), 256, 0, stream>>>(ctx, WoT, proj, 4096, 1024, 1024);
  k_ln_res<<<4096, 256, 0, stream>>>(x, proj, g1, b1, mhaB);
  k_gemm_bt_n64<1><<<dim3(32, 16), 256, 0, stream>>>(mhaB, OwB, lin, 4096, 1024, 1024);
  k_ln2<<<4096, 256, 0, stream>>>(lin, mhaB, out_b, g2, b2, out);
}